// Round 9
// baseline (271.502 us; speedup 1.0000x reference)
//
#include <hip/hip_runtime.h>
#include <hip/hip_bf16.h>
#include <math.h>

typedef unsigned short u16;
typedef short bf16x8 __attribute__((ext_vector_type(8)));
typedef float f32x4 __attribute__((ext_vector_type(4)));

#define NB 8
#define NN 56          // h == w
#define M2 112         // 2n
#define EMB 192
#define D1 576
#define TOK (NB*NN*NN) // 25088

__device__ __forceinline__ float bf2f(unsigned int u) {
    union { unsigned int i; float f; } v; v.i = u << 16; return v.f;
}
__device__ __forceinline__ u16 f2bf(float f) {
    union { float f; unsigned int i; } v; v.f = f;
    unsigned int x = v.i;
    return (u16)((x + 0x7fffu + ((x >> 16) & 1u)) >> 16);
}
__device__ __forceinline__ float silu(float x) {
    return x / (1.0f + __expf(-x));
}
__device__ __forceinline__ void async16(void* lds, const void* g) {
    __builtin_amdgcn_global_load_lds(
        (const __attribute__((address_space(1))) void*)g,
        (__attribute__((address_space(3))) void*)lds, 16, 0, 0);
}

// ---------------- K0: fp32 -> bf16 convert (x, pw, qw, vw, ow) ------------
#define XCH (TOK*EMB/4)
#define WCH (D1*EMB/4)
__global__ __launch_bounds__(256) void convert_kernel(
    const float* __restrict__ x,
    const float* __restrict__ pw, const float* __restrict__ qw,
    const float* __restrict__ vw, const float* __restrict__ ow,
    u16* __restrict__ xb, u16* __restrict__ wb, u16* __restrict__ owb)
{
    int tid = blockIdx.x * 256 + threadIdx.x;
    const float* src; u16* dst; int off;
    if (tid < XCH) { src = x; dst = xb; off = tid; }
    else {
        int r = tid - XCH;
        int seg = r / WCH; off = r % WCH;
        if (seg == 0)      { src = pw; dst = wb; }
        else if (seg == 1) { src = qw; dst = wb + D1*EMB; }
        else if (seg == 2) { src = vw; dst = wb + 2*D1*EMB; }
        else if (seg == 3) { src = ow; dst = owb; }
        else return;
    }
    float4 f = *(const float4*)(src + off * 4);
    ushort4 o;
    o.x = f2bf(f.x); o.y = f2bf(f.y); o.z = f2bf(f.z); o.w = f2bf(f.w);
    *(ushort4*)(dst + off * 4) = o;
}

// ---------------- K1: RPE MLP + decay -> A1, A2 (fp32, 112 x 576 each) ----
__global__ __launch_bounds__(576) void rpe_kernel(
    const float* __restrict__ slope,
    const float* w0a, const float* b0a, const float* wsa, const float* bsa,
    const float* woa, const float* boa,
    const float* w0b, const float* b0b, const float* wsb, const float* bsb,
    const float* wob, const float* bob,
    float* __restrict__ A1, float* __restrict__ A2)
{
    int wq  = blockIdx.x / M2;
    int row = blockIdx.x % M2;
    const float* w0 = wq ? w0b : w0a;  const float* b0 = wq ? b0b : b0a;
    const float* ws = wq ? wsb : wsa;  const float* bs = wq ? bsb : bsa;
    const float* wo = wq ? wob : woa;  const float* bo = wq ? bob : boa;
    float* A = wq ? A2 : A1;

    float tval = (row == 0 || row == 56) ? 0.0f
               : (row < 56 ? (float)row : -(float)(row - 56));
    int kexp = (row == 0 || row == 56) ? 0 : (row < 56 ? row : 112 - row);

    __shared__ float h[32], g[32];
    int t = threadIdx.x;
    if (t < 32) h[t] = tval * w0[t] + b0[t];
    __syncthreads();
    for (int L = 0; L < 3; L++) {
        if (t < 32) g[t] = fmaxf(h[t], 0.0f);
        __syncthreads();
        float hn = 0.0f;
        if (t < 32) {
            hn = bs[L * 32 + t];
            for (int k = 0; k < 32; k++)
                hn = fmaf(g[k], ws[(L * 32 + t) * 32 + k], hn);
        }
        __syncthreads();
        if (t < 32) h[t] = hn;
        __syncthreads();
    }
    if (t < 32) g[t] = fmaxf(h[t], 0.0f);
    __syncthreads();

    float o = bo[t];
    for (int k = 0; k < 32; k++)
        o = fmaf(g[k], wo[t * 32 + k], o);

    float sl = slope[t];
    sl = 0.95f + 0.05f * fminf(fmaxf(sl, 0.0f), 1.0f);
    float dec = powf(sl, (float)kexp);
    A[row * D1 + t] = o * dec;
}

// ---------------- K2: MFMA proj, writes P_T / QV_T (d-major) --------------
// M=TOK, N=576(d), K=192. Tile 128x64, BK=64, 4 waves 2x2.
// C layout: lane holds 4 consecutive tokens (q*4+r) at fixed d -> direct
// ushort4 stores to X_T[d][token], no LDS repack.
__global__ __launch_bounds__(256) void proj_kernel(
    const u16* __restrict__ xb, const u16* __restrict__ wb,
    const float* __restrict__ pb, const float* __restrict__ qb,
    const float* __restrict__ vb,
    u16* __restrict__ P_T, u16* __restrict__ QV_T)
{
    __shared__ u16 lds[20480];          // 40 KB: As 8192 u16, Bs 12288 u16
    u16* As = lds;
    u16* Bs = lds + 8192;
    int m0 = blockIdx.x * 128, n0 = blockIdx.y * 64;
    int t = threadIdx.x;
    int l = t & 63, wave = t >> 6;
    int wm = wave >> 1, wn = wave & 1;
    int col16 = l & 15, q = l >> 4;

    f32x4 accp[4][2], accq[4][2], accv[4][2];
    #pragma unroll
    for (int i = 0; i < 4; i++)
        #pragma unroll
        for (int j = 0; j < 2; j++) {
            accp[i][j] = (f32x4){0,0,0,0};
            accq[i][j] = (f32x4){0,0,0,0};
            accv[i][j] = (f32x4){0,0,0,0};
        }

    for (int k0 = 0; k0 < EMB; k0 += 64) {
        #pragma unroll
        for (int ii = 0; ii < 4; ii++) {
            int slot = (ii * 4 + wave) * 64 + l;
            int r = slot >> 3, s = slot & 7;
            int g = s ^ (r & 7);
            async16(&As[slot * 8], xb + (m0 + r) * EMB + k0 + g * 8);
        }
        #pragma unroll
        for (int ii = 0; ii < 6; ii++) {
            int slot = (ii * 4 + wave) * 64 + l;
            int mat = slot >> 9, cc = slot & 511;
            int r = cc >> 3, s = cc & 7;
            int g = s ^ (r & 7);
            async16(&Bs[slot * 8],
                    wb + mat * (D1 * EMB) + (n0 + r) * EMB + k0 + g * 8);
        }
        __syncthreads();

        #pragma unroll
        for (int kk = 0; kk < 2; kk++) {
            bf16x8 af[4];
            #pragma unroll
            for (int mt = 0; mt < 4; mt++) {
                int row = wm * 64 + mt * 16 + col16;
                int sw = (q + 4 * kk) ^ (col16 & 7);
                af[mt] = *(const bf16x8*)&As[row * 64 + sw * 8];
            }
            bf16x8 bfr[3][2];
            #pragma unroll
            for (int mat = 0; mat < 3; mat++)
                #pragma unroll
                for (int nt = 0; nt < 2; nt++) {
                    int row = wn * 32 + nt * 16 + col16;
                    int sw = (q + 4 * kk) ^ (col16 & 7);
                    bfr[mat][nt] = *(const bf16x8*)&Bs[mat * 4096 + row * 64 + sw * 8];
                }
            #pragma unroll
            for (int mt = 0; mt < 4; mt++)
                #pragma unroll
                for (int nt = 0; nt < 2; nt++) {
                    accp[mt][nt] = __builtin_amdgcn_mfma_f32_16x16x32_bf16(
                        af[mt], bfr[0][nt], accp[mt][nt], 0, 0, 0);
                    accq[mt][nt] = __builtin_amdgcn_mfma_f32_16x16x32_bf16(
                        af[mt], bfr[1][nt], accq[mt][nt], 0, 0, 0);
                    accv[mt][nt] = __builtin_amdgcn_mfma_f32_16x16x32_bf16(
                        af[mt], bfr[2][nt], accv[mt][nt], 0, 0, 0);
                }
        }
        __syncthreads();
    }

    // transposed epilogue: d-major stores
    #pragma unroll
    for (int nt = 0; nt < 2; nt++) {
        int n = n0 + wn * 32 + nt * 16 + col16;       // d index
        float pbv = pb[n], qbv = qb[n], vbv = vb[n];
        #pragma unroll
        for (int mt = 0; mt < 4; mt++) {
            int m = m0 + wm * 64 + mt * 16 + q * 4;   // token base (4 consec)
            ushort4 pv, uv;
            pv.x = f2bf(silu(accp[mt][nt][0] + pbv));
            pv.y = f2bf(silu(accp[mt][nt][1] + pbv));
            pv.z = f2bf(silu(accp[mt][nt][2] + pbv));
            pv.w = f2bf(silu(accp[mt][nt][3] + pbv));
            uv.x = f2bf(silu(accq[mt][nt][0] + qbv) * silu(accv[mt][nt][0] + vbv));
            uv.y = f2bf(silu(accq[mt][nt][1] + qbv) * silu(accv[mt][nt][1] + vbv));
            uv.z = f2bf(silu(accq[mt][nt][2] + qbv) * silu(accv[mt][nt][2] + vbv));
            uv.w = f2bf(silu(accq[mt][nt][3] + qbv) * silu(accv[mt][nt][3] + vbv));
            *(ushort4*)&P_T[(size_t)n * TOK + m]  = pv;
            *(ushort4*)&QV_T[(size_t)n * TOK + m] = uv;
        }
    }
}

// ---------------- K3: fused TNO (d-major): U_T = P_T .* (o1 + o2) ---------
// Block = (d, b). Q slab 56x56 in LDS (f32, stride 60), w-conv -> O1 slab,
// h-conv from same Q slab, fused epilogue. A-windows are wave-broadcast
// LDS reads (all lanes of a wave share ig). No O materialization.
__global__ __launch_bounds__(256) void tno_fused(
    const u16* __restrict__ QV_T, const float* __restrict__ A1,
    const float* __restrict__ A2, const u16* __restrict__ P_T,
    u16* __restrict__ U_T)
{
    __shared__ float Qf[56 * 60];
    __shared__ float O1f[56 * 60];
    __shared__ float a1w[111], a2w[111];
    int d = blockIdx.x, b = blockIdx.y;
    int t = threadIdx.x;
    size_t base = (size_t)d * TOK + b * 3136;

    if (t < 111) {
        int lg = t - 55;
        int rowi = lg + (lg < 0 ? 112 : 0);
        a1w[t] = A1[rowi * D1 + d];
        a2w[t] = A2[rowi * D1 + d];
    }
    for (int pos = t; pos < 3136; pos += 256)
        Qf[(pos / 56) * 60 + pos % 56] = bf2f(QV_T[base + pos]);
    __syncthreads();

    int s = t & 63, ig = t >> 6;
    int i0 = ig * 14;

    // pass 1: conv along w (row = s = h), outputs i = i0..i0+13
    if (s < 56) {
        const float* qrow = &Qf[s * 60];
        float acc[14] = {};
        #pragma unroll
        for (int jg = 0; jg < 14; jg++) {
            f32x4 q4 = *(const f32x4*)&qrow[jg * 4];
            float aw[17];
            #pragma unroll
            for (int k = 0; k < 17; k++)
                aw[k] = a1w[i0 + 52 - 4 * jg + k];
            #pragma unroll
            for (int jj = 0; jj < 4; jj++)
                #pragma unroll
                for (int ii = 0; ii < 14; ii++)
                    acc[ii] = fmaf(aw[ii + 3 - jj], q4[jj], acc[ii]);
        }
        #pragma unroll
        for (int ii = 0; ii < 14; ii++)
            O1f[s * 60 + i0 + ii] = acc[ii];
    }
    __syncthreads();

    // pass 2: conv along h (col = s = w), outputs h = i0..i0+13; fuse U
    if (s < 56) {
        float acc[14] = {};
        #pragma unroll
        for (int jg = 0; jg < 14; jg++) {
            float q0 = Qf[(4 * jg + 0) * 60 + s];
            float q1 = Qf[(4 * jg + 1) * 60 + s];
            float q2 = Qf[(4 * jg + 2) * 60 + s];
            float q3 = Qf[(4 * jg + 3) * 60 + s];
            float aw[17];
            #pragma unroll
            for (int k = 0; k < 17; k++)
                aw[k] = a2w[i0 + 52 - 4 * jg + k];
            #pragma unroll
            for (int ii = 0; ii < 14; ii++) {
                acc[ii] = fmaf(aw[ii + 3], q0, acc[ii]);
                acc[ii] = fmaf(aw[ii + 2], q1, acc[ii]);
                acc[ii] = fmaf(aw[ii + 1], q2, acc[ii]);
                acc[ii] = fmaf(aw[ii + 0], q3, acc[ii]);
            }
        }
        #pragma unroll
        for (int ii = 0; ii < 14; ii++) {
            int h = i0 + ii;
            int pos = h * 56 + s;
            float o = O1f[h * 60 + s] + acc[ii];
            float p = bf2f(P_T[base + pos]);
            U_T[base + pos] = f2bf(p * o);
        }
    }
}

// ---------------- K4: transpose U_T (d-major) -> U (d-innermost) ----------
__global__ __launch_bounds__(256) void transp_kernel(
    const u16* __restrict__ U_T, u16* __restrict__ U)
{
    __shared__ u16 tile[64 * 72];
    int t = threadIdx.x;
    int t0 = blockIdx.x * 64;      // token base
    int d0 = blockIdx.y * 64;      // d base
    {
        int dr = t >> 2, c = t & 3;
        #pragma unroll
        for (int h = 0; h < 2; h++) {
            int cc = c + h * 4;
            uint4 v = *(const uint4*)(U_T + (size_t)(d0 + dr) * TOK + t0 + cc * 8);
            *(uint4*)&tile[dr * 72 + cc * 8] = v;
        }
    }
    __syncthreads();
    {
        int tr = t & 63, c4 = t >> 6;   // wave-uniform c4 -> 2-way LDS reads
        u16 vals[16];
        #pragma unroll
        for (int k = 0; k < 16; k++)
            vals[k] = tile[(c4 * 16 + k) * 72 + tr];
        u16* dst = U + (size_t)(t0 + tr) * D1 + d0 + c4 * 16;
        *(uint4*)(dst)     = *(uint4*)&vals[0];
        *(uint4*)(dst + 8) = *(uint4*)&vals[8];
    }
}

// ---------------- K5: MFMA outproj: out = U @ ow^T + ob (unchanged) -------
__global__ __launch_bounds__(256) void outproj_kernel(
    const u16* __restrict__ U, const u16* __restrict__ owb,
    const float* __restrict__ ob, float* __restrict__ out)
{
    __shared__ char ldsraw[36864];
    u16* As = (u16*)ldsraw;
    u16* Bs = (u16*)(ldsraw + 16384);
    int m0 = blockIdx.x * 128, n0 = blockIdx.y * 64;
    int t = threadIdx.x;
    int l = t & 63, wave = t >> 6;
    int wm = wave >> 1, wn = wave & 1;
    int col16 = l & 15, q = l >> 4;

    f32x4 acc[4][2];
    #pragma unroll
    for (int i = 0; i < 4; i++)
        #pragma unroll
        for (int j = 0; j < 2; j++) acc[i][j] = (f32x4){0,0,0,0};

    for (int k0 = 0; k0 < D1; k0 += 64) {
        #pragma unroll
        for (int ii = 0; ii < 4; ii++) {
            int slot = (ii * 4 + wave) * 64 + l;
            int r = slot >> 3, s = slot & 7;
            int g = s ^ (r & 7);
            async16(&As[slot * 8], U + (m0 + r) * D1 + k0 + g * 8);
        }
        #pragma unroll
        for (int ii = 0; ii < 2; ii++) {
            int slot = (ii * 4 + wave) * 64 + l;
            int r = slot >> 3, s = slot & 7;
            int g = s ^ (r & 7);
            async16(&Bs[slot * 8], owb + (n0 + r) * D1 + k0 + g * 8);
        }
        __syncthreads();

        #pragma unroll
        for (int kk = 0; kk < 2; kk++) {
            int sw = (q + 4 * kk) ^ (col16 & 7);
            bf16x8 af[4];
            #pragma unroll
            for (int mt = 0; mt < 4; mt++)
                af[mt] = *(const bf16x8*)&As[(wm * 64 + mt * 16 + col16) * 64 + sw * 8];
            bf16x8 bfr[2];
            #pragma unroll
            for (int nt = 0; nt < 2; nt++)
                bfr[nt] = *(const bf16x8*)&Bs[(wn * 32 + nt * 16 + col16) * 64 + sw * 8];
            #pragma unroll
            for (int mt = 0; mt < 4; mt++)
                #pragma unroll
                for (int nt = 0; nt < 2; nt++)
                    acc[mt][nt] = __builtin_amdgcn_mfma_f32_16x16x32_bf16(
                        af[mt], bfr[nt], acc[mt][nt], 0, 0, 0);
        }
        __syncthreads();
    }

    float* scr = (float*)ldsraw + wave * 2304;
    float obv[2];
    #pragma unroll
    for (int nt = 0; nt < 2; nt++)
        obv[nt] = ob[n0 + wn * 32 + nt * 16 + col16];
    #pragma unroll
    for (int mt = 0; mt < 4; mt++)
        #pragma unroll
        for (int nt = 0; nt < 2; nt++)
            #pragma unroll
            for (int r = 0; r < 4; r++)
                scr[(mt * 16 + q * 4 + r) * 36 + nt * 16 + col16] =
                    acc[mt][nt][r] + obv[nt];
    #pragma unroll
    for (int k = 0; k < 8; k++) {
        int row = k * 8 + (l >> 3), cs = (l & 7) * 4;
        f32x4 v = *(const f32x4*)&scr[row * 36 + cs];
        *(f32x4*)&out[(m0 + wm * 64 + row) * EMB + n0 + wn * 32 + cs] = v;
    }
}

extern "C" void kernel_launch(void* const* d_in, const int* in_sizes, int n_in,
                              void* d_out, int out_size, void* d_ws, size_t ws_size,
                              hipStream_t stream)
{
    (void)in_sizes; (void)n_in; (void)out_size; (void)ws_size;
    const float* x     = (const float*)d_in[0];
    const float* p_w   = (const float*)d_in[1];
    const float* p_b   = (const float*)d_in[2];
    const float* q_w   = (const float*)d_in[3];
    const float* q_b   = (const float*)d_in[4];
    const float* v_w   = (const float*)d_in[5];
    const float* v_b   = (const float*)d_in[6];
    const float* o_w   = (const float*)d_in[7];
    const float* o_b   = (const float*)d_in[8];
    const float* slope = (const float*)d_in[9];
    const float* t1_w0 = (const float*)d_in[10];
    const float* t1_b0 = (const float*)d_in[11];
    const float* t1_ws = (const float*)d_in[12];
    const float* t1_bs = (const float*)d_in[13];
    const float* t1_wo = (const float*)d_in[14];
    const float* t1_bo = (const float*)d_in[15];
    const float* t2_w0 = (const float*)d_in[16];
    const float* t2_b0 = (const float*)d_in[17];
    const float* t2_ws = (const float*)d_in[18];
    const float* t2_bs = (const float*)d_in[19];
    const float* t2_wo = (const float*)d_in[20];
    const float* t2_bo = (const float*)d_in[21];

    char* ws = (char*)d_ws;
    float* A1  = (float*)ws;                     // 258048 B
    float* A2  = (float*)(ws + 258048);          // 258048 B
    u16*   PU  = (u16*)(ws + 516096);            // 28901376 B (P_T, later U)
    u16*   QVT = (u16*)(ws + 29417472);          // 28901376 B (QV_T d-major)
    u16*   UT  = (u16*)(ws + 58318848);          // 28901376 B (U_T d-major)
    u16*   xb  = (u16*)(ws + 87220224);          // 9633792 B
    u16*   wb  = (u16*)(ws + 96854016);          // 663552 B
    u16*   owb = (u16*)(ws + 97517568);          // 221184 B

    convert_kernel<<<(XCH + 4*WCH + 255) / 256, 256, 0, stream>>>(
        x, p_w, q_w, v_w, o_w, xb, wb, owb);
    rpe_kernel<<<224, 576, 0, stream>>>(slope,
        t1_w0, t1_b0, t1_ws, t1_bs, t1_wo, t1_bo,
        t2_w0, t2_b0, t2_ws, t2_bs, t2_wo, t2_bo, A1, A2);
    proj_kernel<<<dim3(TOK / 128, D1 / 64), 256, 0, stream>>>(
        xb, wb, p_b, q_b, v_b, PU, QVT);
    tno_fused<<<dim3(D1, NB), 256, 0, stream>>>(QVT, A1, A2, PU, UT);
    transp_kernel<<<dim3(TOK / 64, D1 / 64), 256, 0, stream>>>(UT, PU);
    outproj_kernel<<<dim3(TOK / 128, EMB / 64), 256, 0, stream>>>(
        PU, owb, o_b, (float*)d_out);
}

// Round 10
// 218.106 us; speedup vs baseline: 1.2448x; 1.2448x over previous
//
#include <hip/hip_runtime.h>
#include <hip/hip_bf16.h>
#include <math.h>

typedef unsigned short u16;
typedef short bf16x8 __attribute__((ext_vector_type(8)));
typedef float f32x4 __attribute__((ext_vector_type(4)));

#define NB 8
#define NN 56          // h == w
#define M2 112         // 2n
#define EMB 192
#define D1 576
#define TOK (NB*NN*NN) // 25088

__device__ __forceinline__ float bf2f(unsigned int u) {
    union { unsigned int i; float f; } v; v.i = u << 16; return v.f;
}
__device__ __forceinline__ u16 f2bf(float f) {
    union { float f; unsigned int i; } v; v.f = f;
    unsigned int x = v.i;
    return (u16)((x + 0x7fffu + ((x >> 16) & 1u)) >> 16);
}
__device__ __forceinline__ float silu(float x) {
    return x / (1.0f + __expf(-x));
}
__device__ __forceinline__ void async16(void* lds, const void* g) {
    __builtin_amdgcn_global_load_lds(
        (const __attribute__((address_space(1))) void*)g,
        (__attribute__((address_space(3))) void*)lds, 16, 0, 0);
}

// ---------------- K0: fp32 -> bf16 convert (x, pw, qw, vw, ow) ------------
#define XCH (TOK*EMB/4)
#define WCH (D1*EMB/4)
__global__ __launch_bounds__(256) void convert_kernel(
    const float* __restrict__ x,
    const float* __restrict__ pw, const float* __restrict__ qw,
    const float* __restrict__ vw, const float* __restrict__ ow,
    u16* __restrict__ xb, u16* __restrict__ wb, u16* __restrict__ owb)
{
    int tid = blockIdx.x * 256 + threadIdx.x;
    const float* src; u16* dst; int off;
    if (tid < XCH) { src = x; dst = xb; off = tid; }
    else {
        int r = tid - XCH;
        int seg = r / WCH; off = r % WCH;
        if (seg == 0)      { src = pw; dst = wb; }
        else if (seg == 1) { src = qw; dst = wb + D1*EMB; }
        else if (seg == 2) { src = vw; dst = wb + 2*D1*EMB; }
        else if (seg == 3) { src = ow; dst = owb; }
        else return;
    }
    float4 f = *(const float4*)(src + off * 4);
    ushort4 o;
    o.x = f2bf(f.x); o.y = f2bf(f.y); o.z = f2bf(f.z); o.w = f2bf(f.w);
    *(ushort4*)(dst + off * 4) = o;
}

// ---------------- K1: RPE MLP + decay -> A1, A2 (fp32, 112 x 576 each) ----
__global__ __launch_bounds__(576) void rpe_kernel(
    const float* __restrict__ slope,
    const float* w0a, const float* b0a, const float* wsa, const float* bsa,
    const float* woa, const float* boa,
    const float* w0b, const float* b0b, const float* wsb, const float* bsb,
    const float* wob, const float* bob,
    float* __restrict__ A1, float* __restrict__ A2)
{
    int wq  = blockIdx.x / M2;
    int row = blockIdx.x % M2;
    const float* w0 = wq ? w0b : w0a;  const float* b0 = wq ? b0b : b0a;
    const float* ws = wq ? wsb : wsa;  const float* bs = wq ? bsb : bsa;
    const float* wo = wq ? wob : woa;  const float* bo = wq ? bob : boa;
    float* A = wq ? A2 : A1;

    float tval = (row == 0 || row == 56) ? 0.0f
               : (row < 56 ? (float)row : -(float)(row - 56));
    int kexp = (row == 0 || row == 56) ? 0 : (row < 56 ? row : 112 - row);

    __shared__ float h[32], g[32];
    int t = threadIdx.x;
    if (t < 32) h[t] = tval * w0[t] + b0[t];
    __syncthreads();
    for (int L = 0; L < 3; L++) {
        if (t < 32) g[t] = fmaxf(h[t], 0.0f);
        __syncthreads();
        float hn = 0.0f;
        if (t < 32) {
            hn = bs[L * 32 + t];
            for (int k = 0; k < 32; k++)
                hn = fmaf(g[k], ws[(L * 32 + t) * 32 + k], hn);
        }
        __syncthreads();
        if (t < 32) h[t] = hn;
        __syncthreads();
    }
    if (t < 32) g[t] = fmaxf(h[t], 0.0f);
    __syncthreads();

    float o = bo[t];
    for (int k = 0; k < 32; k++)
        o = fmaf(g[k], wo[t * 32 + k], o);

    float sl = slope[t];
    sl = 0.95f + 0.05f * fminf(fmaxf(sl, 0.0f), 1.0f);
    float dec = powf(sl, (float)kexp);
    A[row * D1 + t] = o * dec;
}

// ---------------- K1b: build Toeplitz matrices T[d][64][64] bf16 ----------
// T[i][j] = a_d[i-j] for i,j < 56, else 0 (zero-pad guards MFMA K-padding).
__global__ __launch_bounds__(256) void tbuild_kernel(
    const float* __restrict__ A1, const float* __restrict__ A2,
    u16* __restrict__ T1t, u16* __restrict__ T2t)
{
    int d = blockIdx.x;
    const float* src = blockIdx.y ? A2 : A1;
    u16* dst = blockIdx.y ? T2t : T1t;
    __shared__ float win[111];
    int t = threadIdx.x;
    if (t < 111) {
        int lag = t - 55;
        int rowi = lag + (lag < 0 ? 112 : 0);
        win[t] = src[rowi * D1 + d];
    }
    __syncthreads();
    int i = t >> 2, jq = (t & 3) * 16;
    u16 vals[16];
    #pragma unroll
    for (int jj = 0; jj < 16; jj++) {
        int j = jq + jj;
        float v = (i < 56 && j < 56) ? win[i - j + 55] : 0.0f;
        vals[jj] = f2bf(v);
    }
    u16* out = dst + ((size_t)d * 64 + i) * 64 + jq;
    *(uint4*)(out)     = *(uint4*)&vals[0];
    *(uint4*)(out + 8) = *(uint4*)&vals[8];
}

// ---------------- K2: MFMA proj, d-major P_T/QV_T, coalesced stores -------
__global__ __launch_bounds__(256) void proj_kernel(
    const u16* __restrict__ xb, const u16* __restrict__ wb,
    const float* __restrict__ pb, const float* __restrict__ qb,
    const float* __restrict__ vb,
    u16* __restrict__ P_T, u16* __restrict__ QV_T)
{
    __shared__ u16 lds[20480];          // 40 KB: As 8192 u16, Bs 12288 u16
    u16* As = lds;
    u16* Bs = lds + 8192;
    int m0 = blockIdx.x * 128, n0 = blockIdx.y * 64;
    int t = threadIdx.x;
    int l = t & 63, wave = t >> 6;
    int wm = wave >> 1, wn = wave & 1;
    int col16 = l & 15, q = l >> 4;

    f32x4 accp[4][2], accq[4][2], accv[4][2];
    #pragma unroll
    for (int i = 0; i < 4; i++)
        #pragma unroll
        for (int j = 0; j < 2; j++) {
            accp[i][j] = (f32x4){0,0,0,0};
            accq[i][j] = (f32x4){0,0,0,0};
            accv[i][j] = (f32x4){0,0,0,0};
        }

    for (int k0 = 0; k0 < EMB; k0 += 64) {
        #pragma unroll
        for (int ii = 0; ii < 4; ii++) {
            int slot = (ii * 4 + wave) * 64 + l;
            int r = slot >> 3, s = slot & 7;
            int g = s ^ (r & 7);
            async16(&As[slot * 8], xb + (m0 + r) * EMB + k0 + g * 8);
        }
        #pragma unroll
        for (int ii = 0; ii < 6; ii++) {
            int slot = (ii * 4 + wave) * 64 + l;
            int mat = slot >> 9, cc = slot & 511;
            int r = cc >> 3, s = cc & 7;
            int g = s ^ (r & 7);
            async16(&Bs[slot * 8],
                    wb + mat * (D1 * EMB) + (n0 + r) * EMB + k0 + g * 8);
        }
        __syncthreads();

        #pragma unroll
        for (int kk = 0; kk < 2; kk++) {
            bf16x8 af[4];
            #pragma unroll
            for (int mt = 0; mt < 4; mt++) {
                int row = wm * 64 + mt * 16 + col16;
                int sw = (q + 4 * kk) ^ (col16 & 7);
                af[mt] = *(const bf16x8*)&As[row * 64 + sw * 8];
            }
            bf16x8 bfr[3][2];
            #pragma unroll
            for (int mat = 0; mat < 3; mat++)
                #pragma unroll
                for (int nt = 0; nt < 2; nt++) {
                    int row = wn * 32 + nt * 16 + col16;
                    int sw = (q + 4 * kk) ^ (col16 & 7);
                    bfr[mat][nt] = *(const bf16x8*)&Bs[mat * 4096 + row * 64 + sw * 8];
                }
            #pragma unroll
            for (int mt = 0; mt < 4; mt++)
                #pragma unroll
                for (int nt = 0; nt < 2; nt++) {
                    accp[mt][nt] = __builtin_amdgcn_mfma_f32_16x16x32_bf16(
                        af[mt], bfr[0][nt], accp[mt][nt], 0, 0, 0);
                    accq[mt][nt] = __builtin_amdgcn_mfma_f32_16x16x32_bf16(
                        af[mt], bfr[1][nt], accq[mt][nt], 0, 0, 0);
                    accv[mt][nt] = __builtin_amdgcn_mfma_f32_16x16x32_bf16(
                        af[mt], bfr[2][nt], accv[mt][nt], 0, 0, 0);
                }
        }
        __syncthreads();
    }

    // epilogue: per-wave LDS repack (stride 42 u16) -> coalesced d-major
    u16* scr = lds + wave * 2688;       // 64 tok x 42
    float pbv[2], qbv[2], vbv[2];
    #pragma unroll
    for (int nt = 0; nt < 2; nt++) {
        int n = n0 + wn * 32 + nt * 16 + col16;
        pbv[nt] = pb[n]; qbv[nt] = qb[n]; vbv[nt] = vb[n];
    }
    // ---- P ----
    #pragma unroll
    for (int mt = 0; mt < 4; mt++)
        #pragma unroll
        for (int nt = 0; nt < 2; nt++)
            #pragma unroll
            for (int r = 0; r < 4; r++)
                scr[(mt * 16 + q * 4 + r) * 42 + nt * 16 + col16] =
                    f2bf(silu(accp[mt][nt][r] + pbv[nt]));
    #pragma unroll
    for (int dl = 0; dl < 32; dl++)
        P_T[(size_t)(n0 + wn * 32 + dl) * TOK + m0 + wm * 64 + l] =
            scr[l * 42 + dl];
    // ---- QV ----
    #pragma unroll
    for (int mt = 0; mt < 4; mt++)
        #pragma unroll
        for (int nt = 0; nt < 2; nt++)
            #pragma unroll
            for (int r = 0; r < 4; r++)
                scr[(mt * 16 + q * 4 + r) * 42 + nt * 16 + col16] =
                    f2bf(silu(accq[mt][nt][r] + qbv[nt]) *
                         silu(accv[mt][nt][r] + vbv[nt]));
    #pragma unroll
    for (int dl = 0; dl < 32; dl++)
        QV_T[(size_t)(n0 + wn * 32 + dl) * TOK + m0 + wm * 64 + l] =
            scr[l * 42 + dl];
}

// ---------------- K3: fused MFMA TNO (d-major), U_T = P_T .* (o1+o2) ------
// Block = (d, b). Wave = n-block nt. Pass1: o1 = T1_d @ Q (B rows = h),
// Pass2: o2 = T2_d @ Q^T (B rows = w). o1 slab in LDS; coalesced sweep.
__global__ __launch_bounds__(256) void tno_mfma(
    const u16* __restrict__ QV_T, const u16* __restrict__ T1t,
    const u16* __restrict__ T2t, const u16* __restrict__ P_T,
    u16* __restrict__ U_T)
{
    __shared__ u16 T1s[4096];       // 64 rows x 8 swizzled 16B chunks
    __shared__ u16 T2s[4096];
    __shared__ u16 Qn[64 * 72];     // [h][j=w], k-cols 56..63 zeroed
    __shared__ u16 Qt[64 * 72];     // [w][h], k-cols 56..63 zeroed
    __shared__ float O1f[56 * 68];  // spatial [h][w] f32
    int d = blockIdx.x, b = blockIdx.y;
    int t = threadIdx.x;
    size_t base = (size_t)d * TOK + (size_t)b * 3136;

    #pragma unroll
    for (int k = 0; k < 2; k++) {
        int slot = t + k * 256;
        int i = slot >> 3, s = slot & 7;
        int g = s ^ (i & 7);
        async16(&T1s[slot * 8], T1t + ((size_t)d * 64 + i) * 64 + g * 8);
        async16(&T2s[slot * 8], T2t + ((size_t)d * 64 + i) * 64 + g * 8);
    }
    for (int c = t; c < 392; c += 256) {      // 56 rows x 7 chunks of 8
        int h = c / 7, w8 = (c % 7) * 8;
        uint4 v = *(const uint4*)(QV_T + base + c * 8);
        *(uint4*)&Qn[h * 72 + w8] = v;
        u16 e[8];
        *(uint4*)e = v;
        #pragma unroll
        for (int k = 0; k < 8; k++)
            Qt[(w8 + k) * 72 + h] = e[k];
    }
    if (t < 56) {                              // zero K-padding cols 56..63
        uint4 z = {0, 0, 0, 0};
        *(uint4*)&Qn[t * 72 + 56] = z;
        *(uint4*)&Qt[t * 72 + 56] = z;
    }
    __syncthreads();

    int l = t & 63, wave = t >> 6;             // wave = nt (n-block)
    int col16 = l & 15, q = l >> 4;

    f32x4 acc1[4], acc2[4];
    #pragma unroll
    for (int i = 0; i < 4; i++) { acc1[i] = (f32x4){0,0,0,0}; acc2[i] = (f32x4){0,0,0,0}; }

    #pragma unroll
    for (int kk = 0; kk < 2; kk++) {
        int sw = ((q + 4 * kk) ^ (col16 & 7)) * 8;
        bf16x8 bq1 = *(const bf16x8*)&Qn[(wave * 16 + col16) * 72 + kk * 32 + q * 8];
        bf16x8 bq2 = *(const bf16x8*)&Qt[(wave * 16 + col16) * 72 + kk * 32 + q * 8];
        #pragma unroll
        for (int mt = 0; mt < 4; mt++) {
            bf16x8 a1 = *(const bf16x8*)&T1s[(mt * 16 + col16) * 64 + sw];
            bf16x8 a2 = *(const bf16x8*)&T2s[(mt * 16 + col16) * 64 + sw];
            acc1[mt] = __builtin_amdgcn_mfma_f32_16x16x32_bf16(a1, bq1, acc1[mt], 0, 0, 0);
            acc2[mt] = __builtin_amdgcn_mfma_f32_16x16x32_bf16(a2, bq2, acc2[mt], 0, 0, 0);
        }
    }

    // pass1 C: m = w-out, n = h  -> O1f[h][w]
    {
        int n = wave * 16 + col16;
        if (n < 56) {
            #pragma unroll
            for (int mt = 0; mt < 4; mt++)
                #pragma unroll
                for (int r = 0; r < 4; r++) {
                    int m = mt * 16 + q * 4 + r;
                    if (m < 56) O1f[n * 68 + m] = acc1[mt][r];
                }
        }
    }
    __syncthreads();
    // pass2 C: m = h-out, n = w  -> O1f[h][w] += o2 (in place)
    {
        int n = wave * 16 + col16;
        if (n < 56) {
            #pragma unroll
            for (int mt = 0; mt < 4; mt++)
                #pragma unroll
                for (int r = 0; r < 4; r++) {
                    int m = mt * 16 + q * 4 + r;
                    if (m < 56) O1f[m * 68 + n] += acc2[mt][r];
                }
        }
    }
    __syncthreads();
    // sweep: U_T = P_T .* (o1+o2), fully coalesced
    for (int c = t; c < 392; c += 256) {
        int h = c / 7, w8 = (c % 7) * 8;
        f32x4 s0 = *(const f32x4*)&O1f[h * 68 + w8];
        f32x4 s1 = *(const f32x4*)&O1f[h * 68 + w8 + 4];
        uint4 pv = *(const uint4*)(P_T + base + c * 8);
        u16 pe[8];
        *(uint4*)pe = pv;
        u16 ue[8];
        #pragma unroll
        for (int k = 0; k < 4; k++) ue[k] = f2bf(bf2f(pe[k]) * s0[k]);
        #pragma unroll
        for (int k = 0; k < 4; k++) ue[4 + k] = f2bf(bf2f(pe[4 + k]) * s1[k]);
        *(uint4*)(U_T + base + c * 8) = *(uint4*)ue;
    }
}

// ---------------- K4: transpose U_T (d-major) -> U (d-innermost) ----------
__global__ __launch_bounds__(256) void transp_kernel(
    const u16* __restrict__ U_T, u16* __restrict__ U)
{
    __shared__ u16 tile[64 * 72];
    int t = threadIdx.x;
    int t0 = blockIdx.x * 64;      // token base
    int d0 = blockIdx.y * 64;      // d base
    {
        int dr = t >> 2, c = t & 3;
        #pragma unroll
        for (int h = 0; h < 2; h++) {
            int cc = c + h * 4;
            uint4 v = *(const uint4*)(U_T + (size_t)(d0 + dr) * TOK + t0 + cc * 8);
            *(uint4*)&tile[dr * 72 + cc * 8] = v;
        }
    }
    __syncthreads();
    {
        int tr = t & 63, c4 = t >> 6;
        u16 vals[16];
        #pragma unroll
        for (int k = 0; k < 16; k++)
            vals[k] = tile[(c4 * 16 + k) * 72 + tr];
        u16* dst = U + (size_t)(t0 + tr) * D1 + d0 + c4 * 16;
        *(uint4*)(dst)     = *(uint4*)&vals[0];
        *(uint4*)(dst + 8) = *(uint4*)&vals[8];
    }
}

// ---------------- K5: MFMA outproj: out = U @ ow^T + ob -------------------
__global__ __launch_bounds__(256) void outproj_kernel(
    const u16* __restrict__ U, const u16* __restrict__ owb,
    const float* __restrict__ ob, float* __restrict__ out)
{
    __shared__ char ldsraw[36864];
    u16* As = (u16*)ldsraw;
    u16* Bs = (u16*)(ldsraw + 16384);
    int m0 = blockIdx.x * 128, n0 = blockIdx.y * 64;
    int t = threadIdx.x;
    int l = t & 63, wave = t >> 6;
    int wm = wave >> 1, wn = wave & 1;
    int col16 = l & 15, q = l >> 4;

    f32x4 acc[4][2];
    #pragma unroll
    for (int i = 0; i < 4; i++)
        #pragma unroll
        for (int j = 0; j < 2; j++) acc[i][j] = (f32x4){0,0,0,0};

    for (int k0 = 0; k0 < D1; k0 += 64) {
        #pragma unroll
        for (int ii = 0; ii < 4; ii++) {
            int slot = (ii * 4 + wave) * 64 + l;
            int r = slot >> 3, s = slot & 7;
            int g = s ^ (r & 7);
            async16(&As[slot * 8], U + (m0 + r) * D1 + k0 + g * 8);
        }
        #pragma unroll
        for (int ii = 0; ii < 2; ii++) {
            int slot = (ii * 4 + wave) * 64 + l;
            int r = slot >> 3, s = slot & 7;
            int g = s ^ (r & 7);
            async16(&Bs[slot * 8], owb + (n0 + r) * D1 + k0 + g * 8);
        }
        __syncthreads();

        #pragma unroll
        for (int kk = 0; kk < 2; kk++) {
            int sw = (q + 4 * kk) ^ (col16 & 7);
            bf16x8 af[4];
            #pragma unroll
            for (int mt = 0; mt < 4; mt++)
                af[mt] = *(const bf16x8*)&As[(wm * 64 + mt * 16 + col16) * 64 + sw * 8];
            bf16x8 bfr[2];
            #pragma unroll
            for (int nt = 0; nt < 2; nt++)
                bfr[nt] = *(const bf16x8*)&Bs[(wn * 32 + nt * 16 + col16) * 64 + sw * 8];
            #pragma unroll
            for (int mt = 0; mt < 4; mt++)
                #pragma unroll
                for (int nt = 0; nt < 2; nt++)
                    acc[mt][nt] = __builtin_amdgcn_mfma_f32_16x16x32_bf16(
                        af[mt], bfr[nt], acc[mt][nt], 0, 0, 0);
        }
        __syncthreads();
    }

    float* scr = (float*)ldsraw + wave * 2304;
    float obv[2];
    #pragma unroll
    for (int nt = 0; nt < 2; nt++)
        obv[nt] = ob[n0 + wn * 32 + nt * 16 + col16];
    #pragma unroll
    for (int mt = 0; mt < 4; mt++)
        #pragma unroll
        for (int nt = 0; nt < 2; nt++)
            #pragma unroll
            for (int r = 0; r < 4; r++)
                scr[(mt * 16 + q * 4 + r) * 36 + nt * 16 + col16] =
                    acc[mt][nt][r] + obv[nt];
    #pragma unroll
    for (int k = 0; k < 8; k++) {
        int row = k * 8 + (l >> 3), cs = (l & 7) * 4;
        f32x4 v = *(const f32x4*)&scr[row * 36 + cs];
        *(f32x4*)&out[(m0 + wm * 64 + row) * EMB + n0 + wn * 32 + cs] = v;
    }
}

extern "C" void kernel_launch(void* const* d_in, const int* in_sizes, int n_in,
                              void* d_out, int out_size, void* d_ws, size_t ws_size,
                              hipStream_t stream)
{
    (void)in_sizes; (void)n_in; (void)out_size; (void)ws_size;
    const float* x     = (const float*)d_in[0];
    const float* p_w   = (const float*)d_in[1];
    const float* p_b   = (const float*)d_in[2];
    const float* q_w   = (const float*)d_in[3];
    const float* q_b   = (const float*)d_in[4];
    const float* v_w   = (const float*)d_in[5];
    const float* v_b   = (const float*)d_in[6];
    const float* o_w   = (const float*)d_in[7];
    const float* o_b   = (const float*)d_in[8];
    const float* slope = (const float*)d_in[9];
    const float* t1_w0 = (const float*)d_in[10];
    const float* t1_b0 = (const float*)d_in[11];
    const float* t1_ws = (const float*)d_in[12];
    const float* t1_bs = (const float*)d_in[13];
    const float* t1_wo = (const float*)d_in[14];
    const float* t1_bo = (const float*)d_in[15];
    const float* t2_w0 = (const float*)d_in[16];
    const float* t2_b0 = (const float*)d_in[17];
    const float* t2_ws = (const float*)d_in[18];
    const float* t2_bs = (const float*)d_in[19];
    const float* t2_wo = (const float*)d_in[20];
    const float* t2_bo = (const float*)d_in[21];

    char* ws = (char*)d_ws;
    float* A1  = (float*)ws;                     // 258048 B
    float* A2  = (float*)(ws + 258048);          // 258048 B
    u16*   PU  = (u16*)(ws + 516096);            // 28901376 B (P_T, later U)
    u16*   QVT = (u16*)(ws + 29417472);          // 28901376 B
    u16*   UT  = (u16*)(ws + 58318848);          // 28901376 B
    u16*   xb  = (u16*)(ws + 87220224);          // 9633792 B
    u16*   wb  = (u16*)(ws + 96854016);          // 663552 B
    u16*   owb = (u16*)(ws + 97517568);          // 221184 B
    u16*   T1t = (u16*)(ws + 97738752);          // 4718592 B
    u16*   T2t = (u16*)(ws + 102457344);         // 4718592 B

    convert_kernel<<<(XCH + 4*WCH + 255) / 256, 256, 0, stream>>>(
        x, p_w, q_w, v_w, o_w, xb, wb, owb);
    rpe_kernel<<<224, 576, 0, stream>>>(slope,
        t1_w0, t1_b0, t1_ws, t1_bs, t1_wo, t1_bo,
        t2_w0, t2_b0, t2_ws, t2_bs, t2_wo, t2_bo, A1, A2);
    tbuild_kernel<<<dim3(576, 2), 256, 0, stream>>>(A1, A2, T1t, T2t);
    proj_kernel<<<dim3(TOK / 128, D1 / 64), 256, 0, stream>>>(
        xb, wb, p_b, q_b, v_b, PU, QVT);
    tno_mfma<<<dim3(D1, NB), 256, 0, stream>>>(QVT, T1t, T2t, PU, UT);
    transp_kernel<<<dim3(TOK / 64, D1 / 64), 256, 0, stream>>>(UT, PU);
    outproj_kernel<<<dim3(TOK / 128, EMB / 64), 256, 0, stream>>>(
        PU, owb, o_b, (float*)d_out);
}